// Round 1
// baseline (105.781 us; speedup 1.0000x reference)
//
#include <hip/hip_runtime.h>

// SpatialTransformer 2D->2D bilinear sampling.
// inputs: [NR, FH, FW, FDIM] f32; im_x/im_y: [NR, NV] f32 pixel coords.
// out: [NR, NV, FDIM] f32 (reshape to (NR,1,120,160,FDIM) is a flat view).

constexpr int NR   = 4;
constexpr int FH   = 90;
constexpr int FW   = 160;
constexpr int FDIM = 512;
constexpr int NV   = 120 * 160;    // 19200 ground-plane points per view
constexpr int C4   = FDIM / 4;     // 128 float4 chunks per point

__global__ __launch_bounds__(256) void st_bilinear_kernel(
    const float* __restrict__ inp,
    const float* __restrict__ imx,
    const float* __restrict__ imy,
    float* __restrict__ out)
{
    int gid = blockIdx.x * blockDim.x + threadIdx.x;
    int pt  = gid >> 7;      // which (r, v) point; 128 threads per point
    int c4  = gid & (C4 - 1);
    if (pt >= NR * NV) return;

    int r = pt / NV;

    // Same-address broadcast load across the 128 threads of a point.
    float x = imx[pt];
    float y = imy[pt];
    x = fminf(fmaxf(x, 0.0f), (float)(FW - 1));
    y = fminf(fmaxf(y, 0.0f), (float)(FH - 1));

    float x0f = floorf(x), y0f = floorf(y);
    int x0 = (int)x0f,  y0 = (int)y0f;
    int x1 = min(x0 + 1, FW - 1);
    int y1 = min(y0 + 1, FH - 1);

    // Replicate reference weight formulation exactly (handles the
    // x==FW-1 degenerate case the same way: both weights go to 0).
    float wx1 = (float)x1 - x;   // weight toward x0 column
    float wx0 = x - x0f;         // weight toward x1 column
    float wy1 = (float)y1 - y;
    float wy0 = y - y0f;
    float wa = wx1 * wy1;
    float wb = wx1 * wy0;
    float wc = wx0 * wy1;
    float wd = wx0 * wy0;

    const float4* base = (const float4*)inp;
    int rb = r * FH;
    size_t ia = (size_t)((rb + y0) * FW + x0) * C4 + c4;
    size_t ib = (size_t)((rb + y1) * FW + x0) * C4 + c4;
    size_t ic = (size_t)((rb + y0) * FW + x1) * C4 + c4;
    size_t id = (size_t)((rb + y1) * FW + x1) * C4 + c4;

    float4 a = base[ia];
    float4 b = base[ib];
    float4 c = base[ic];
    float4 d = base[id];

    float4 o;
    o.x = wa * a.x + wb * b.x + wc * c.x + wd * d.x;
    o.y = wa * a.y + wb * b.y + wc * c.y + wd * d.y;
    o.z = wa * a.z + wb * b.z + wc * c.z + wd * d.z;
    o.w = wa * a.w + wb * b.w + wc * c.w + wd * d.w;

    ((float4*)out)[gid] = o;
}

extern "C" void kernel_launch(void* const* d_in, const int* in_sizes, int n_in,
                              void* d_out, int out_size, void* d_ws, size_t ws_size,
                              hipStream_t stream) {
    const float* inp = (const float*)d_in[0];
    const float* imx = (const float*)d_in[1];
    const float* imy = (const float*)d_in[2];
    float* out = (float*)d_out;

    int total_threads = NR * NV * C4;            // 9,830,400
    dim3 block(256);
    dim3 grid((total_threads + 255) / 256);      // 38,400 blocks

    hipLaunchKernelGGL(st_bilinear_kernel, grid, block, 0, stream,
                       inp, imx, imy, out);
}

// Round 2
// 97.602 us; speedup vs baseline: 1.0838x; 1.0838x over previous
//
#include <hip/hip_runtime.h>

// SpatialTransformer 2D->2D bilinear sampling, with point reordering for L2 locality.
// inputs: [NR, FH, FW, FDIM] f32; im_x/im_y: [NR, NV] f32 pixel coords.
// out: [NR, NV, FDIM] f32.

constexpr int NR   = 4;
constexpr int FH   = 90;
constexpr int FW   = 160;
constexpr int FDIM = 512;
constexpr int NV   = 120 * 160;    // 19200 points per view
constexpr int NPTS = NR * NV;      // 76800
constexpr int C4   = FDIM / 4;     // 128 float4 chunks per point

// Binning for the counting sort: bin = (view, y0/4, x0/8).
constexpr int BY   = 4;
constexpr int BX   = 8;
constexpr int NGY  = (FH + BY - 1) / BY;   // 23
constexpr int NGX  = (FW + BX - 1) / BX;   // 20
constexpr int NBINS = NR * NGY * NGX;      // 1840

__device__ __forceinline__ int point_bin(const float* __restrict__ imx,
                                         const float* __restrict__ imy, int pt) {
    int r = pt / NV;
    float x = imx[pt], y = imy[pt];
    x = fminf(fmaxf(x, 0.0f), (float)(FW - 1));
    y = fminf(fmaxf(y, 0.0f), (float)(FH - 1));
    int x0 = (int)floorf(x);
    int y0 = (int)floorf(y);
    return (r * NGY + (y0 >> 2)) * NGX + (x0 >> 3);
}

__global__ void k_zero(int* __restrict__ binCnt) {
    int i = blockIdx.x * blockDim.x + threadIdx.x;
    if (i < NBINS) binCnt[i] = 0;
}

__global__ void k_hist(const float* __restrict__ imx, const float* __restrict__ imy,
                       int* __restrict__ binCnt, int* __restrict__ ptBin) {
    int pt = blockIdx.x * blockDim.x + threadIdx.x;
    if (pt >= NPTS) return;
    int b = point_bin(imx, imy, pt);
    ptBin[pt] = b;
    atomicAdd(&binCnt[b], 1);
}

// Single-block exclusive scan over NBINS (=1840) counters.
__global__ __launch_bounds__(256) void k_scan(const int* __restrict__ binCnt,
                                              int* __restrict__ binOff) {
    constexpr int CHUNK = (NBINS + 255) / 256;  // 8
    __shared__ int sums[256];
    int t = threadIdx.x;
    int base = t * CHUNK;
    int local[CHUNK];
    int s = 0;
    for (int i = 0; i < CHUNK; ++i) {
        int idx = base + i;
        int v = (idx < NBINS) ? binCnt[idx] : 0;
        local[i] = s;
        s += v;
    }
    sums[t] = s;
    __syncthreads();
    // Hillis-Steele inclusive scan of the 256 chunk sums.
    for (int off = 1; off < 256; off <<= 1) {
        int v = (t >= off) ? sums[t - off] : 0;
        __syncthreads();
        sums[t] += v;
        __syncthreads();
    }
    int prefix = (t == 0) ? 0 : sums[t - 1];
    for (int i = 0; i < CHUNK; ++i) {
        int idx = base + i;
        if (idx < NBINS) binOff[idx] = prefix + local[i];
    }
}

__global__ void k_scatter(const int* __restrict__ ptBin, int* __restrict__ binOff,
                          int* __restrict__ perm) {
    int pt = blockIdx.x * blockDim.x + threadIdx.x;
    if (pt >= NPTS) return;
    int b = ptBin[pt];
    int slot = atomicAdd(&binOff[b], 1);
    perm[slot] = pt;
}

__device__ __forceinline__ void bilinear_body(const float* __restrict__ inp,
                                              const float* __restrict__ imx,
                                              const float* __restrict__ imy,
                                              float* __restrict__ out,
                                              int pt, int c4) {
    int r = pt / NV;
    float x = imx[pt];
    float y = imy[pt];
    x = fminf(fmaxf(x, 0.0f), (float)(FW - 1));
    y = fminf(fmaxf(y, 0.0f), (float)(FH - 1));

    float x0f = floorf(x), y0f = floorf(y);
    int x0 = (int)x0f, y0 = (int)y0f;
    int x1 = min(x0 + 1, FW - 1);
    int y1 = min(y0 + 1, FH - 1);

    float wx1 = (float)x1 - x;
    float wx0 = x - x0f;
    float wy1 = (float)y1 - y;
    float wy0 = y - y0f;
    float wa = wx1 * wy1;
    float wb = wx1 * wy0;
    float wc = wx0 * wy1;
    float wd = wx0 * wy0;

    const float4* base = (const float4*)inp;
    int rb = r * FH;
    size_t ia = (size_t)((rb + y0) * FW + x0) * C4 + c4;
    size_t ib = (size_t)((rb + y1) * FW + x0) * C4 + c4;
    size_t ic = (size_t)((rb + y0) * FW + x1) * C4 + c4;
    size_t id = (size_t)((rb + y1) * FW + x1) * C4 + c4;

    float4 a = base[ia];
    float4 b = base[ib];
    float4 c = base[ic];
    float4 d = base[id];

    float4 o;
    o.x = wa * a.x + wb * b.x + wc * c.x + wd * d.x;
    o.y = wa * a.y + wb * b.y + wc * c.y + wd * d.y;
    o.z = wa * a.z + wb * b.z + wc * c.z + wd * d.z;
    o.w = wa * a.w + wb * b.w + wc * c.w + wd * d.w;

    ((float4*)out)[(size_t)pt * C4 + c4] = o;
}

// Sorted main kernel: 2 points per 256-thread block, processed in bin-sorted
// order, with chunked XCD swizzle (block p -> XCD p%8 round-robin assumption;
// remap so each XCD gets a contiguous sorted range -> small L2 working set).
__global__ __launch_bounds__(256) void st_bilinear_sorted(
    const float* __restrict__ inp,
    const float* __restrict__ imx,
    const float* __restrict__ imy,
    const int* __restrict__ perm,
    float* __restrict__ out)
{
    int p = blockIdx.x;
    int cpx = gridDim.x >> 3;            // 38400/8 = 4800, exact
    int l = (p & 7) * cpx + (p >> 3);    // bijective chunked swizzle
    int sidx = l * 2 + (threadIdx.x >> 7);
    int c4 = threadIdx.x & (C4 - 1);
    int pt = perm[sidx];
    bilinear_body(inp, imx, imy, out, pt, c4);
}

// Fallback (no workspace): unsorted direct kernel.
__global__ __launch_bounds__(256) void st_bilinear_direct(
    const float* __restrict__ inp,
    const float* __restrict__ imx,
    const float* __restrict__ imy,
    float* __restrict__ out)
{
    int gid = blockIdx.x * blockDim.x + threadIdx.x;
    int pt = gid >> 7;
    int c4 = gid & (C4 - 1);
    if (pt >= NPTS) return;
    bilinear_body(inp, imx, imy, out, pt, c4);
}

extern "C" void kernel_launch(void* const* d_in, const int* in_sizes, int n_in,
                              void* d_out, int out_size, void* d_ws, size_t ws_size,
                              hipStream_t stream) {
    const float* inp = (const float*)d_in[0];
    const float* imx = (const float*)d_in[1];
    const float* imy = (const float*)d_in[2];
    float* out = (float*)d_out;

    // Workspace layout: binCnt[NBINS] | binOff[NBINS] | ptBin[NPTS] | perm[NPTS]
    size_t need = (size_t)(2 * NBINS + 2 * NPTS) * sizeof(int);
    int nblocks = (NPTS * C4) / 256;   // 38400, divisible by 8

    if (ws_size < need) {
        hipLaunchKernelGGL(st_bilinear_direct, dim3(nblocks), dim3(256), 0, stream,
                           inp, imx, imy, out);
        return;
    }

    int* binCnt = (int*)d_ws;
    int* binOff = binCnt + NBINS;
    int* ptBin  = binOff + NBINS;
    int* perm   = ptBin + NPTS;

    hipLaunchKernelGGL(k_zero, dim3((NBINS + 255) / 256), dim3(256), 0, stream, binCnt);
    hipLaunchKernelGGL(k_hist, dim3((NPTS + 255) / 256), dim3(256), 0, stream,
                       imx, imy, binCnt, ptBin);
    hipLaunchKernelGGL(k_scan, dim3(1), dim3(256), 0, stream, binCnt, binOff);
    hipLaunchKernelGGL(k_scatter, dim3((NPTS + 255) / 256), dim3(256), 0, stream,
                       ptBin, binOff, perm);
    hipLaunchKernelGGL(st_bilinear_sorted, dim3(nblocks), dim3(256), 0, stream,
                       inp, imx, imy, perm, out);
}

// Round 3
// 71.284 us; speedup vs baseline: 1.4839x; 1.3692x over previous
//
#include <hip/hip_runtime.h>

// SpatialTransformer 2D->2D bilinear sampling.
// Strategy: counting-sort points into (view, y0/3, x0/5) bins; one block per
// bin stages the bin's 4x6-cell halo footprint (48 KB) into LDS, then serves
// all its points' 4-corner gathers from LDS. Global reads become sequential
// streams (177 MB vs 629 MB gather); stores are nontemporal.

typedef float f32x4 __attribute__((ext_vector_type(4)));

constexpr int NR   = 4;
constexpr int FH   = 90;
constexpr int FW   = 160;
constexpr int FDIM = 512;
constexpr int NV   = 120 * 160;    // 19200 points per view
constexpr int NPTS = NR * NV;      // 76800
constexpr int C4   = FDIM / 4;     // 128 float4 chunks per point

constexpr int BY   = 3;            // bin height in cells
constexpr int BX   = 5;            // bin width in cells
constexpr int NGY  = FH / BY;      // 30 (exact)
constexpr int NGX  = FW / BX;      // 32 (exact)
constexpr int NBINS = NR * NGY * NGX;  // 3840 (divisible by 8 and 256)
constexpr int SY   = BY + 1;       // staged rows  = 4
constexpr int SX   = BX + 1;       // staged cols  = 6
constexpr int SCELLS = SY * SX;    // 24 cells -> 48 KB LDS

__device__ __forceinline__ int point_bin(const float* __restrict__ imx,
                                         const float* __restrict__ imy, int pt) {
    int r = pt / NV;
    float x = imx[pt], y = imy[pt];
    x = fminf(fmaxf(x, 0.0f), (float)(FW - 1));
    y = fminf(fmaxf(y, 0.0f), (float)(FH - 1));
    int x0 = (int)floorf(x);
    int y0 = (int)floorf(y);
    return (r * NGY + y0 / BY) * NGX + x0 / BX;
}

__global__ void k_zero(int* __restrict__ binCnt) {
    int i = blockIdx.x * blockDim.x + threadIdx.x;
    if (i < NBINS) binCnt[i] = 0;
}

__global__ void k_hist(const float* __restrict__ imx, const float* __restrict__ imy,
                       int* __restrict__ binCnt) {
    int pt = blockIdx.x * blockDim.x + threadIdx.x;
    if (pt >= NPTS) return;
    atomicAdd(&binCnt[point_bin(imx, imy, pt)], 1);
}

// Single-block exclusive scan over NBINS (=3840) counters -> binStart + binCursor.
__global__ __launch_bounds__(256) void k_scan(const int* __restrict__ binCnt,
                                              int* __restrict__ binStart,
                                              int* __restrict__ binCursor) {
    constexpr int CHUNK = NBINS / 256;  // 15
    __shared__ int sums[256];
    int t = threadIdx.x;
    int base = t * CHUNK;
    int local[CHUNK];
    int s = 0;
    for (int i = 0; i < CHUNK; ++i) {
        int v = binCnt[base + i];
        local[i] = s;
        s += v;
    }
    sums[t] = s;
    __syncthreads();
    for (int off = 1; off < 256; off <<= 1) {
        int v = (t >= off) ? sums[t - off] : 0;
        __syncthreads();
        sums[t] += v;
        __syncthreads();
    }
    int prefix = (t == 0) ? 0 : sums[t - 1];
    for (int i = 0; i < CHUNK; ++i) {
        int v = prefix + local[i];
        binStart[base + i]  = v;
        binCursor[base + i] = v;
    }
}

__global__ void k_scatter(const float* __restrict__ imx, const float* __restrict__ imy,
                          int* __restrict__ binCursor, int* __restrict__ perm) {
    int pt = blockIdx.x * blockDim.x + threadIdx.x;
    if (pt >= NPTS) return;
    int b = point_bin(imx, imy, pt);
    int slot = atomicAdd(&binCursor[b], 1);
    perm[slot] = pt;
}

// One block per bin: stage halo footprint to LDS, serve points from LDS.
__global__ __launch_bounds__(256) void st_bins(
    const float* __restrict__ inp,
    const float* __restrict__ imx,
    const float* __restrict__ imy,
    const int* __restrict__ perm,
    const int* __restrict__ binStart,
    const int* __restrict__ binCnt,
    float* __restrict__ out)
{
    __shared__ f32x4 lds[SCELLS * C4];   // 24 * 128 * 16 B = 48 KB

    int p = blockIdx.x;
    // Chunked XCD swizzle: contiguous bin ranges per XCD for halo L2 reuse.
    int b = (p & 7) * (NBINS >> 3) + (p >> 3);

    int r   = b / (NGY * NGX);
    int by0 = (b / NGX % NGY) * BY;
    int bx0 = (b % NGX) * BX;
    int tid = threadIdx.x;

    const f32x4* in4 = (const f32x4*)inp;
    #pragma unroll
    for (int i = 0; i < (SCELLS * C4) / 256; ++i) {
        int idx  = tid + i * 256;
        int cell = idx >> 7;
        int c4   = idx & (C4 - 1);
        int ry   = cell / SX;
        int rx   = cell - ry * SX;
        int gy   = min(by0 + ry, FH - 1);   // edge bins: duplicate last row/col
        int gx   = min(bx0 + rx, FW - 1);
        lds[idx] = in4[(size_t)((r * FH + gy) * FW + gx) * C4 + c4];
    }

    int start = binStart[b];
    int cnt   = binCnt[b];
    __syncthreads();

    int half = tid >> 7;          // 2 points processed per iteration
    int c4   = tid & (C4 - 1);
    f32x4* out4 = (f32x4*)out;

    for (int i = half; i < cnt; i += 2) {
        int pt = perm[start + i];
        float x = imx[pt];
        float y = imy[pt];
        x = fminf(fmaxf(x, 0.0f), (float)(FW - 1));
        y = fminf(fmaxf(y, 0.0f), (float)(FH - 1));

        float x0f = floorf(x), y0f = floorf(y);
        int x0 = (int)x0f, y0 = (int)y0f;
        int x1 = min(x0 + 1, FW - 1);
        int y1 = min(y0 + 1, FH - 1);

        float wx1 = (float)x1 - x;
        float wx0 = x - x0f;
        float wy1 = (float)y1 - y;
        float wy0 = y - y0f;
        float wa = wx1 * wy1;
        float wb = wx1 * wy0;
        float wc = wx0 * wy1;
        float wd = wx0 * wy0;

        int ly0 = y0 - by0, ly1 = y1 - by0;
        int lx0 = x0 - bx0, lx1 = x1 - bx0;

        f32x4 A  = lds[((ly0 * SX + lx0) << 7) + c4];
        f32x4 Bv = lds[((ly1 * SX + lx0) << 7) + c4];
        f32x4 Cv = lds[((ly0 * SX + lx1) << 7) + c4];
        f32x4 D  = lds[((ly1 * SX + lx1) << 7) + c4];

        f32x4 o = wa * A + wb * Bv + wc * Cv + wd * D;
        __builtin_nontemporal_store(o, out4 + (size_t)pt * C4 + c4);
    }
}

// Fallback (no workspace): unsorted direct kernel.
__global__ __launch_bounds__(256) void st_bilinear_direct(
    const float* __restrict__ inp,
    const float* __restrict__ imx,
    const float* __restrict__ imy,
    float* __restrict__ out)
{
    int gid = blockIdx.x * blockDim.x + threadIdx.x;
    int pt = gid >> 7;
    int c4 = gid & (C4 - 1);
    if (pt >= NPTS) return;

    int r = pt / NV;
    float x = imx[pt], y = imy[pt];
    x = fminf(fmaxf(x, 0.0f), (float)(FW - 1));
    y = fminf(fmaxf(y, 0.0f), (float)(FH - 1));
    float x0f = floorf(x), y0f = floorf(y);
    int x0 = (int)x0f, y0 = (int)y0f;
    int x1 = min(x0 + 1, FW - 1);
    int y1 = min(y0 + 1, FH - 1);
    float wx1 = (float)x1 - x, wx0 = x - x0f;
    float wy1 = (float)y1 - y, wy0 = y - y0f;
    float wa = wx1 * wy1, wb = wx1 * wy0, wc = wx0 * wy1, wd = wx0 * wy0;

    const f32x4* base = (const f32x4*)inp;
    int rb = r * FH;
    f32x4 a = base[(size_t)((rb + y0) * FW + x0) * C4 + c4];
    f32x4 b = base[(size_t)((rb + y1) * FW + x0) * C4 + c4];
    f32x4 c = base[(size_t)((rb + y0) * FW + x1) * C4 + c4];
    f32x4 d = base[(size_t)((rb + y1) * FW + x1) * C4 + c4];
    f32x4 o = wa * a + wb * b + wc * c + wd * d;
    ((f32x4*)out)[(size_t)pt * C4 + c4] = o;
}

extern "C" void kernel_launch(void* const* d_in, const int* in_sizes, int n_in,
                              void* d_out, int out_size, void* d_ws, size_t ws_size,
                              hipStream_t stream) {
    const float* inp = (const float*)d_in[0];
    const float* imx = (const float*)d_in[1];
    const float* imy = (const float*)d_in[2];
    float* out = (float*)d_out;

    // Workspace: binCnt | binStart | binCursor | perm
    size_t need = (size_t)(3 * NBINS + NPTS) * sizeof(int);   // ~353 KB

    if (ws_size < need) {
        int nblocks = (NPTS * C4) / 256;
        hipLaunchKernelGGL(st_bilinear_direct, dim3(nblocks), dim3(256), 0, stream,
                           inp, imx, imy, out);
        return;
    }

    int* binCnt    = (int*)d_ws;
    int* binStart  = binCnt + NBINS;
    int* binCursor = binStart + NBINS;
    int* perm      = binCursor + NBINS;

    hipLaunchKernelGGL(k_zero, dim3((NBINS + 255) / 256), dim3(256), 0, stream, binCnt);
    hipLaunchKernelGGL(k_hist, dim3((NPTS + 255) / 256), dim3(256), 0, stream,
                       imx, imy, binCnt);
    hipLaunchKernelGGL(k_scan, dim3(1), dim3(256), 0, stream,
                       binCnt, binStart, binCursor);
    hipLaunchKernelGGL(k_scatter, dim3((NPTS + 255) / 256), dim3(256), 0, stream,
                       imx, imy, binCursor, perm);
    hipLaunchKernelGGL(st_bins, dim3(NBINS), dim3(256), 0, stream,
                       inp, imx, imy, perm, binStart, binCnt, out);
}

// Round 4
// 60.694 us; speedup vs baseline: 1.7428x; 1.1745x over previous
//
#include <hip/hip_runtime.h>

// SpatialTransformer 2D->2D bilinear sampling.
// Pipeline (3 dispatches):
//   k_zero     : zero per-bin counters + overflow counter
//   k_scatter  : single-pass capacity-binned counting scatter; pre-gathers
//                clamped (x,y) into bin-sorted order
//   st_bins    : one block per (view, 3x5-cell) bin; stages the 4x6-cell halo
//                footprint (48 KB) into LDS, serves all 4-corner gathers from
//                LDS, nontemporal stores. Overflow points (slot>=CAP, ~never
//                for uniform coords) handled via direct global gather.

typedef float f32x4 __attribute__((ext_vector_type(4)));

constexpr int NR   = 4;
constexpr int FH   = 90;
constexpr int FW   = 160;
constexpr int FDIM = 512;
constexpr int NV   = 120 * 160;    // 19200 points per view
constexpr int NPTS = NR * NV;      // 76800
constexpr int C4   = FDIM / 4;     // 128 float4 chunks per point

constexpr int BY   = 3;            // bin height in cells
constexpr int BX   = 5;            // bin width in cells
constexpr int NGY  = FH / BY;      // 30
constexpr int NGX  = FW / BX;      // 32
constexpr int NBINS = NR * NGY * NGX;  // 3840
constexpr int SY   = BY + 1;       // 4 staged rows
constexpr int SX   = BX + 1;       // 6 staged cols
constexpr int SCELLS = SY * SX;    // 24 cells -> 48 KB LDS

constexpr int CAP   = 48;          // per-bin slot capacity (lambda=20)
constexpr int OVCAP = 4096;        // overflow list capacity

__global__ void k_zero(int* __restrict__ cnts) {
    int i = blockIdx.x * blockDim.x + threadIdx.x;
    if (i < NBINS + 1) cnts[i] = 0;   // binCnt[NBINS] + ovCnt
}

__global__ void k_scatter(const float* __restrict__ imx, const float* __restrict__ imy,
                          int* __restrict__ binCnt, int* __restrict__ ovCnt,
                          int* __restrict__ perm, float* __restrict__ sX,
                          float* __restrict__ sY, int* __restrict__ ovList) {
    int pt = blockIdx.x * blockDim.x + threadIdx.x;
    if (pt >= NPTS) return;
    int r = pt / NV;
    float x = imx[pt], y = imy[pt];
    x = fminf(fmaxf(x, 0.0f), (float)(FW - 1));
    y = fminf(fmaxf(y, 0.0f), (float)(FH - 1));
    int x0 = (int)floorf(x);
    int y0 = (int)floorf(y);
    int b = (r * NGY + y0 / BY) * NGX + x0 / BX;
    int slot = atomicAdd(&binCnt[b], 1);
    if (slot < CAP) {
        int idx = b * CAP + slot;
        perm[idx] = pt;
        sX[idx] = x;
        sY[idx] = y;
    } else {
        int o = atomicAdd(ovCnt, 1);
        if (o < OVCAP) ovList[o] = pt;
    }
}

__device__ __forceinline__ f32x4 lerp4(f32x4 A, f32x4 B, f32x4 C, f32x4 D,
                                       float wa, float wb, float wc, float wd) {
    return wa * A + wb * B + wc * C + wd * D;
}

__device__ __forceinline__ void weights_and_cells(float x, float y,
                                                  int& x0, int& x1, int& y0, int& y1,
                                                  float& wa, float& wb, float& wc, float& wd) {
    float x0f = floorf(x), y0f = floorf(y);
    x0 = (int)x0f; y0 = (int)y0f;
    x1 = min(x0 + 1, FW - 1);
    y1 = min(y0 + 1, FH - 1);
    float wx1 = (float)x1 - x;
    float wx0 = x - x0f;
    float wy1 = (float)y1 - y;
    float wy0 = y - y0f;
    wa = wx1 * wy1; wb = wx1 * wy0; wc = wx0 * wy1; wd = wx0 * wy0;
}

__global__ __launch_bounds__(256) void st_bins(
    const float* __restrict__ inp,
    const int* __restrict__ binCnt,
    const int* __restrict__ ovCnt,
    const int* __restrict__ perm,
    const float* __restrict__ sX,
    const float* __restrict__ sY,
    const int* __restrict__ ovList,
    const float* __restrict__ imx,
    const float* __restrict__ imy,
    float* __restrict__ out)
{
    __shared__ f32x4 lds[SCELLS * C4];   // 48 KB

    int p = blockIdx.x;
    int b = (p & 7) * (NBINS >> 3) + (p >> 3);   // chunked XCD swizzle

    int r   = b / (NGY * NGX);
    int by0 = (b / NGX % NGY) * BY;
    int bx0 = (b % NGX) * BX;
    int tid = threadIdx.x;

    const f32x4* in4 = (const f32x4*)inp;
    #pragma unroll
    for (int i = 0; i < (SCELLS * C4) / 256; ++i) {
        int idx  = tid + i * 256;
        int cell = idx >> 7;
        int c4   = idx & (C4 - 1);
        int ry   = cell / SX;
        int rx   = cell - ry * SX;
        int gy   = min(by0 + ry, FH - 1);
        int gx   = min(bx0 + rx, FW - 1);
        lds[idx] = in4[(size_t)((r * FH + gy) * FW + gx) * C4 + c4];
    }

    int cnt  = min(binCnt[b], CAP);
    int base = b * CAP;
    __syncthreads();

    int half = tid >> 7;
    int c4   = tid & (C4 - 1);
    f32x4* out4 = (f32x4*)out;

    int i = half;
    // 2-point unrolled main loop (per 128-thread group): 8 LDS reads in flight.
    for (; i + 2 < cnt; i += 4) {
        int   ptA = perm[base + i];
        float xA  = sX[base + i], yA = sY[base + i];
        int   ptB = perm[base + i + 2];
        float xB  = sX[base + i + 2], yB = sY[base + i + 2];

        int x0A, x1A, y0A, y1A, x0B, x1B, y0B, y1B;
        float waA, wbA, wcA, wdA, waB, wbB, wcB, wdB;
        weights_and_cells(xA, yA, x0A, x1A, y0A, y1A, waA, wbA, wcA, wdA);
        weights_and_cells(xB, yB, x0B, x1B, y0B, y1B, waB, wbB, wcB, wdB);

        f32x4 Aa = lds[(((y0A - by0) * SX + (x0A - bx0)) << 7) + c4];
        f32x4 Ab = lds[(((y1A - by0) * SX + (x0A - bx0)) << 7) + c4];
        f32x4 Ac = lds[(((y0A - by0) * SX + (x1A - bx0)) << 7) + c4];
        f32x4 Ad = lds[(((y1A - by0) * SX + (x1A - bx0)) << 7) + c4];
        f32x4 Ba = lds[(((y0B - by0) * SX + (x0B - bx0)) << 7) + c4];
        f32x4 Bb = lds[(((y1B - by0) * SX + (x0B - bx0)) << 7) + c4];
        f32x4 Bc = lds[(((y0B - by0) * SX + (x1B - bx0)) << 7) + c4];
        f32x4 Bd = lds[(((y1B - by0) * SX + (x1B - bx0)) << 7) + c4];

        __builtin_nontemporal_store(lerp4(Aa, Ab, Ac, Ad, waA, wbA, wcA, wdA),
                                    out4 + (size_t)ptA * C4 + c4);
        __builtin_nontemporal_store(lerp4(Ba, Bb, Bc, Bd, waB, wbB, wcB, wdB),
                                    out4 + (size_t)ptB * C4 + c4);
    }
    if (i < cnt) {
        int   pt = perm[base + i];
        float x  = sX[base + i], y = sY[base + i];
        int x0, x1, y0, y1; float wa, wb, wc, wd;
        weights_and_cells(x, y, x0, x1, y0, y1, wa, wb, wc, wd);
        f32x4 A = lds[(((y0 - by0) * SX + (x0 - bx0)) << 7) + c4];
        f32x4 B = lds[(((y1 - by0) * SX + (x0 - bx0)) << 7) + c4];
        f32x4 C = lds[(((y0 - by0) * SX + (x1 - bx0)) << 7) + c4];
        f32x4 D = lds[(((y1 - by0) * SX + (x1 - bx0)) << 7) + c4];
        __builtin_nontemporal_store(lerp4(A, B, C, D, wa, wb, wc, wd),
                                    out4 + (size_t)pt * C4 + c4);
    }

    // Cold path: overflow points (slot >= CAP) via direct global gather.
    int ov = min(*ovCnt, OVCAP);
    for (int j = b; j < ov; j += NBINS) {
        if (half != 0) continue;
        int pt = ovList[j];
        int rr = pt / NV;
        float x = imx[pt], y = imy[pt];
        x = fminf(fmaxf(x, 0.0f), (float)(FW - 1));
        y = fminf(fmaxf(y, 0.0f), (float)(FH - 1));
        int x0, x1, y0, y1; float wa, wb, wc, wd;
        weights_and_cells(x, y, x0, x1, y0, y1, wa, wb, wc, wd);
        int rb = rr * FH;
        f32x4 A = in4[(size_t)((rb + y0) * FW + x0) * C4 + c4];
        f32x4 B = in4[(size_t)((rb + y1) * FW + x0) * C4 + c4];
        f32x4 C = in4[(size_t)((rb + y0) * FW + x1) * C4 + c4];
        f32x4 D = in4[(size_t)((rb + y1) * FW + x1) * C4 + c4];
        __builtin_nontemporal_store(lerp4(A, B, C, D, wa, wb, wc, wd),
                                    out4 + (size_t)pt * C4 + c4);
    }
}

// Fallback (workspace too small): unsorted direct kernel.
__global__ __launch_bounds__(256) void st_bilinear_direct(
    const float* __restrict__ inp,
    const float* __restrict__ imx,
    const float* __restrict__ imy,
    float* __restrict__ out)
{
    int gid = blockIdx.x * blockDim.x + threadIdx.x;
    int pt = gid >> 7;
    int c4 = gid & (C4 - 1);
    if (pt >= NPTS) return;
    int r = pt / NV;
    float x = imx[pt], y = imy[pt];
    x = fminf(fmaxf(x, 0.0f), (float)(FW - 1));
    y = fminf(fmaxf(y, 0.0f), (float)(FH - 1));
    int x0, x1, y0, y1; float wa, wb, wc, wd;
    weights_and_cells(x, y, x0, x1, y0, y1, wa, wb, wc, wd);
    const f32x4* base = (const f32x4*)inp;
    int rb = r * FH;
    f32x4 a = base[(size_t)((rb + y0) * FW + x0) * C4 + c4];
    f32x4 b = base[(size_t)((rb + y1) * FW + x0) * C4 + c4];
    f32x4 c = base[(size_t)((rb + y0) * FW + x1) * C4 + c4];
    f32x4 d = base[(size_t)((rb + y1) * FW + x1) * C4 + c4];
    ((f32x4*)out)[(size_t)pt * C4 + c4] = lerp4(a, b, c, d, wa, wb, wc, wd);
}

extern "C" void kernel_launch(void* const* d_in, const int* in_sizes, int n_in,
                              void* d_out, int out_size, void* d_ws, size_t ws_size,
                              hipStream_t stream) {
    const float* inp = (const float*)d_in[0];
    const float* imx = (const float*)d_in[1];
    const float* imy = (const float*)d_in[2];
    float* out = (float*)d_out;

    // ws layout: binCnt[NBINS] | ovCnt[1] | perm[NBINS*CAP] | sX | sY | ovList[OVCAP]
    size_t nInts = (size_t)NBINS + 1 + (size_t)NBINS * CAP * 3 + OVCAP;
    size_t need  = nInts * sizeof(int);   // ~2.25 MB

    if (ws_size < need) {
        int nblocks = (NPTS * C4) / 256;
        hipLaunchKernelGGL(st_bilinear_direct, dim3(nblocks), dim3(256), 0, stream,
                           inp, imx, imy, out);
        return;
    }

    int*   binCnt = (int*)d_ws;
    int*   ovCnt  = binCnt + NBINS;
    int*   perm   = ovCnt + 1;
    float* sX     = (float*)(perm + NBINS * CAP);
    float* sY     = sX + NBINS * CAP;
    int*   ovList = (int*)(sY + NBINS * CAP);

    hipLaunchKernelGGL(k_zero, dim3((NBINS + 1 + 255) / 256), dim3(256), 0, stream,
                       binCnt);
    hipLaunchKernelGGL(k_scatter, dim3((NPTS + 255) / 256), dim3(256), 0, stream,
                       imx, imy, binCnt, ovCnt, perm, sX, sY, ovList);
    hipLaunchKernelGGL(st_bins, dim3(NBINS), dim3(256), 0, stream,
                       inp, binCnt, ovCnt, perm, sX, sY, ovList, imx, imy, out);
}

// Round 5
// 58.868 us; speedup vs baseline: 1.7969x; 1.0310x over previous
//
#include <hip/hip_runtime.h>

// SpatialTransformer 2D->2D bilinear sampling.
// Pipeline (3 dispatches):
//   k_zero     : zero per-bin counters + overflow counter
//   k_scatter  : single-pass capacity-binned counting scatter; pre-gathers
//                clamped (x,y) into bin-sorted order
//   st_bins    : one 512-thread block per (view, 3x5-cell) bin; stages the
//                4x6-cell halo footprint (48 KB) into LDS via async
//                global_load_lds, stages point metadata into LDS, serves all
//                4-corner gathers from LDS, nontemporal stores.
//                Overflow points (slot>=CAP) handled via direct global gather.

typedef float f32x4 __attribute__((ext_vector_type(4)));

#define GLOBAL_AS __attribute__((address_space(1)))
#define LDS_AS    __attribute__((address_space(3)))

constexpr int NR   = 4;
constexpr int FH   = 90;
constexpr int FW   = 160;
constexpr int FDIM = 512;
constexpr int NV   = 120 * 160;    // 19200 points per view
constexpr int NPTS = NR * NV;      // 76800
constexpr int C4   = FDIM / 4;     // 128 float4 chunks per point

constexpr int BY   = 3;            // bin height in cells
constexpr int BX   = 5;            // bin width in cells
constexpr int NGY  = FH / BY;      // 30
constexpr int NGX  = FW / BX;      // 32
constexpr int NBINS = NR * NGY * NGX;  // 3840
constexpr int SY   = BY + 1;       // 4 staged rows
constexpr int SX   = BX + 1;       // 6 staged cols
constexpr int SCELLS = SY * SX;    // 24 cells -> 48 KB LDS

constexpr int CAP   = 48;          // per-bin slot capacity (lambda=20)
constexpr int OVCAP = 4096;        // overflow list capacity
constexpr int TPB   = 512;         // main-kernel threads per block

__global__ void k_zero(int* __restrict__ cnts) {
    int i = blockIdx.x * blockDim.x + threadIdx.x;
    if (i < NBINS + 1) cnts[i] = 0;   // binCnt[NBINS] + ovCnt
}

__global__ void k_scatter(const float* __restrict__ imx, const float* __restrict__ imy,
                          int* __restrict__ binCnt, int* __restrict__ ovCnt,
                          int* __restrict__ perm, float* __restrict__ sX,
                          float* __restrict__ sY, int* __restrict__ ovList) {
    int pt = blockIdx.x * blockDim.x + threadIdx.x;
    if (pt >= NPTS) return;
    int r = pt / NV;
    float x = imx[pt], y = imy[pt];
    x = fminf(fmaxf(x, 0.0f), (float)(FW - 1));
    y = fminf(fmaxf(y, 0.0f), (float)(FH - 1));
    int x0 = (int)floorf(x);
    int y0 = (int)floorf(y);
    int b = (r * NGY + y0 / BY) * NGX + x0 / BX;
    int slot = atomicAdd(&binCnt[b], 1);
    if (slot < CAP) {
        int idx = b * CAP + slot;
        perm[idx] = pt;
        sX[idx] = x;
        sY[idx] = y;
    } else {
        int o = atomicAdd(ovCnt, 1);
        if (o < OVCAP) ovList[o] = pt;
    }
}

__device__ __forceinline__ f32x4 lerp4(f32x4 A, f32x4 B, f32x4 C, f32x4 D,
                                       float wa, float wb, float wc, float wd) {
    return wa * A + wb * B + wc * C + wd * D;
}

__device__ __forceinline__ void weights_and_cells(float x, float y,
                                                  int& x0, int& x1, int& y0, int& y1,
                                                  float& wa, float& wb, float& wc, float& wd) {
    float x0f = floorf(x), y0f = floorf(y);
    x0 = (int)x0f; y0 = (int)y0f;
    x1 = min(x0 + 1, FW - 1);
    y1 = min(y0 + 1, FH - 1);
    float wx1 = (float)x1 - x;
    float wx0 = x - x0f;
    float wy1 = (float)y1 - y;
    float wy0 = y - y0f;
    wa = wx1 * wy1; wb = wx1 * wy0; wc = wx0 * wy1; wd = wx0 * wy0;
}

__global__ __launch_bounds__(TPB) void st_bins(
    const float* __restrict__ inp,
    const int* __restrict__ binCnt,
    const int* __restrict__ ovCnt,
    const int* __restrict__ perm,
    const float* __restrict__ sX,
    const float* __restrict__ sY,
    const int* __restrict__ ovList,
    const float* __restrict__ imx,
    const float* __restrict__ imy,
    float* __restrict__ out)
{
    __shared__ f32x4 lds[SCELLS * C4];   // 48 KB
    __shared__ int   pmS[CAP];
    __shared__ float pxS[CAP];
    __shared__ float pyS[CAP];

    int p = blockIdx.x;
    int b = (p & 7) * (NBINS >> 3) + (p >> 3);   // chunked XCD swizzle

    int r   = b / (NGY * NGX);
    int by0 = (b / NGX % NGY) * BY;
    int bx0 = (b % NGX) * BX;
    int tid = threadIdx.x;

    const f32x4* in4 = (const f32x4*)inp;
    int cnt  = min(binCnt[b], CAP);
    int base = b * CAP;

    // Async staging: 6 iterations x 512 threads x 16B. Per wave: LDS dest is
    // wave-uniform base + lane*16 (linear), global source contiguous per wave.
    #pragma unroll
    for (int i = 0; i < (SCELLS * C4) / TPB; ++i) {
        int idx  = tid + i * TPB;
        int cell = idx >> 7;
        int c4   = idx & (C4 - 1);
        int ry   = cell / SX;
        int rx   = cell - ry * SX;
        int gy   = min(by0 + ry, FH - 1);
        int gx   = min(bx0 + rx, FW - 1);
        const void* gsrc = (const void*)(in4 + (size_t)((r * FH + gy) * FW + gx) * C4 + c4);
        __builtin_amdgcn_global_load_lds(
            (const GLOBAL_AS void*)gsrc,
            (LDS_AS void*)&lds[idx], 16, 0, 0);
    }
    // Stage point metadata into LDS (overlaps with async tile staging).
    if (tid < cnt) {
        pmS[tid] = perm[base + tid];
        pxS[tid] = sX[base + tid];
        pyS[tid] = sY[base + tid];
    }
    __syncthreads();

    int g  = tid >> 7;          // 4 groups of 128 threads
    int c4 = tid & (C4 - 1);
    f32x4* out4 = (f32x4*)out;

    int i = g;
    // 2-point unrolled loop per group: 8 LDS reads in flight.
    for (; i + 4 < cnt; i += 8) {
        int   ptA = pmS[i];
        float xA  = pxS[i], yA = pyS[i];
        int   ptB = pmS[i + 4];
        float xB  = pxS[i + 4], yB = pyS[i + 4];

        int x0A, x1A, y0A, y1A, x0B, x1B, y0B, y1B;
        float waA, wbA, wcA, wdA, waB, wbB, wcB, wdB;
        weights_and_cells(xA, yA, x0A, x1A, y0A, y1A, waA, wbA, wcA, wdA);
        weights_and_cells(xB, yB, x0B, x1B, y0B, y1B, waB, wbB, wcB, wdB);

        f32x4 Aa = lds[(((y0A - by0) * SX + (x0A - bx0)) << 7) + c4];
        f32x4 Ab = lds[(((y1A - by0) * SX + (x0A - bx0)) << 7) + c4];
        f32x4 Ac = lds[(((y0A - by0) * SX + (x1A - bx0)) << 7) + c4];
        f32x4 Ad = lds[(((y1A - by0) * SX + (x1A - bx0)) << 7) + c4];
        f32x4 Ba = lds[(((y0B - by0) * SX + (x0B - bx0)) << 7) + c4];
        f32x4 Bb = lds[(((y1B - by0) * SX + (x0B - bx0)) << 7) + c4];
        f32x4 Bc = lds[(((y0B - by0) * SX + (x1B - bx0)) << 7) + c4];
        f32x4 Bd = lds[(((y1B - by0) * SX + (x1B - bx0)) << 7) + c4];

        __builtin_nontemporal_store(lerp4(Aa, Ab, Ac, Ad, waA, wbA, wcA, wdA),
                                    out4 + (size_t)ptA * C4 + c4);
        __builtin_nontemporal_store(lerp4(Ba, Bb, Bc, Bd, waB, wbB, wcB, wdB),
                                    out4 + (size_t)ptB * C4 + c4);
    }
    if (i < cnt) {
        int   pt = pmS[i];
        float x  = pxS[i], y = pyS[i];
        int x0, x1, y0, y1; float wa, wb, wc, wd;
        weights_and_cells(x, y, x0, x1, y0, y1, wa, wb, wc, wd);
        f32x4 A = lds[(((y0 - by0) * SX + (x0 - bx0)) << 7) + c4];
        f32x4 B = lds[(((y1 - by0) * SX + (x0 - bx0)) << 7) + c4];
        f32x4 C = lds[(((y0 - by0) * SX + (x1 - bx0)) << 7) + c4];
        f32x4 D = lds[(((y1 - by0) * SX + (x1 - bx0)) << 7) + c4];
        __builtin_nontemporal_store(lerp4(A, B, C, D, wa, wb, wc, wd),
                                    out4 + (size_t)pt * C4 + c4);
    }

    // Cold path: overflow points (slot >= CAP) via direct global gather.
    int ov = min(*ovCnt, OVCAP);
    for (int j = b; j < ov; j += NBINS) {
        if (g != 0) continue;
        int pt = ovList[j];
        int rr = pt / NV;
        float x = imx[pt], y = imy[pt];
        x = fminf(fmaxf(x, 0.0f), (float)(FW - 1));
        y = fminf(fmaxf(y, 0.0f), (float)(FH - 1));
        int x0, x1, y0, y1; float wa, wb, wc, wd;
        weights_and_cells(x, y, x0, x1, y0, y1, wa, wb, wc, wd);
        int rb = rr * FH;
        f32x4 A = in4[(size_t)((rb + y0) * FW + x0) * C4 + c4];
        f32x4 B = in4[(size_t)((rb + y1) * FW + x0) * C4 + c4];
        f32x4 C = in4[(size_t)((rb + y0) * FW + x1) * C4 + c4];
        f32x4 D = in4[(size_t)((rb + y1) * FW + x1) * C4 + c4];
        __builtin_nontemporal_store(lerp4(A, B, C, D, wa, wb, wc, wd),
                                    out4 + (size_t)pt * C4 + c4);
    }
}

// Fallback (workspace too small): unsorted direct kernel.
__global__ __launch_bounds__(256) void st_bilinear_direct(
    const float* __restrict__ inp,
    const float* __restrict__ imx,
    const float* __restrict__ imy,
    float* __restrict__ out)
{
    int gid = blockIdx.x * blockDim.x + threadIdx.x;
    int pt = gid >> 7;
    int c4 = gid & (C4 - 1);
    if (pt >= NPTS) return;
    int r = pt / NV;
    float x = imx[pt], y = imy[pt];
    x = fminf(fmaxf(x, 0.0f), (float)(FW - 1));
    y = fminf(fmaxf(y, 0.0f), (float)(FH - 1));
    int x0, x1, y0, y1; float wa, wb, wc, wd;
    weights_and_cells(x, y, x0, x1, y0, y1, wa, wb, wc, wd);
    const f32x4* base = (const f32x4*)inp;
    int rb = r * FH;
    f32x4 a = base[(size_t)((rb + y0) * FW + x0) * C4 + c4];
    f32x4 b = base[(size_t)((rb + y1) * FW + x0) * C4 + c4];
    f32x4 c = base[(size_t)((rb + y0) * FW + x1) * C4 + c4];
    f32x4 d = base[(size_t)((rb + y1) * FW + x1) * C4 + c4];
    ((f32x4*)out)[(size_t)pt * C4 + c4] = lerp4(a, b, c, d, wa, wb, wc, wd);
}

extern "C" void kernel_launch(void* const* d_in, const int* in_sizes, int n_in,
                              void* d_out, int out_size, void* d_ws, size_t ws_size,
                              hipStream_t stream) {
    const float* inp = (const float*)d_in[0];
    const float* imx = (const float*)d_in[1];
    const float* imy = (const float*)d_in[2];
    float* out = (float*)d_out;

    // ws layout: binCnt[NBINS] | ovCnt[1] | perm[NBINS*CAP] | sX | sY | ovList[OVCAP]
    size_t nInts = (size_t)NBINS + 1 + (size_t)NBINS * CAP * 3 + OVCAP;
    size_t need  = nInts * sizeof(int);   // ~2.25 MB

    if (ws_size < need) {
        int nblocks = (NPTS * C4) / 256;
        hipLaunchKernelGGL(st_bilinear_direct, dim3(nblocks), dim3(256), 0, stream,
                           inp, imx, imy, out);
        return;
    }

    int*   binCnt = (int*)d_ws;
    int*   ovCnt  = binCnt + NBINS;
    int*   perm   = ovCnt + 1;
    float* sX     = (float*)(perm + NBINS * CAP);
    float* sY     = sX + NBINS * CAP;
    int*   ovList = (int*)(sY + NBINS * CAP);

    hipLaunchKernelGGL(k_zero, dim3((NBINS + 1 + 255) / 256), dim3(256), 0, stream,
                       binCnt);
    hipLaunchKernelGGL(k_scatter, dim3((NPTS + 255) / 256), dim3(256), 0, stream,
                       imx, imy, binCnt, ovCnt, perm, sX, sY, ovList);
    hipLaunchKernelGGL(st_bins, dim3(NBINS), dim3(TPB), 0, stream,
                       inp, binCnt, ovCnt, perm, sX, sY, ovList, imx, imy, out);
}